// Round 1
// baseline (376.047 us; speedup 1.0000x reference)
//
#include <hip/hip_runtime.h>
#include <cstdint>
#include <cstddef>

#define TDIM 4096       // B*S tokens
#define DDIM 1024
#define HDIM 4096
#define EDIM 8
#define CAPD 2048
#define NSLOT 8192      // T*K
#define NROUTERBLK 1024

typedef _Float16 f16;
typedef _Float16 f16x2 __attribute__((ext_vector_type(2)));
typedef _Float16 f16x4 __attribute__((ext_vector_type(4)));
typedef _Float16 f16x8 __attribute__((ext_vector_type(8)));
typedef float f32x4 __attribute__((ext_vector_type(4)));

__device__ __forceinline__ void gload16(const void* g, void* l) {
  __builtin_amdgcn_global_load_lds(
      (const __attribute__((address_space(1))) unsigned int*)g,
      (__attribute__((address_space(3))) unsigned int*)l, 16, 0, 0);
}

// ---------------- transpose + f32->f16 convert: src (E,R,C) -> dst (E,C,R) ----------------
__global__ void transpose_cvt(const float* __restrict__ src, f16* __restrict__ dst,
                              int R, int C) {
  __shared__ float tile[32][33];
  const int e = blockIdx.z;
  const int c0 = blockIdx.x * 32, r0 = blockIdx.y * 32;
  const int tx = threadIdx.x & 31, ty = threadIdx.x >> 5;   // ty in [0,8)
  const float* s = src + (size_t)e * R * C;
  f16* d = dst + (size_t)e * R * C;
  #pragma unroll
  for (int rr = 0; rr < 32; rr += 8)
    tile[ty + rr][tx] = s[(size_t)(r0 + ty + rr) * C + c0 + tx];
  __syncthreads();
  #pragma unroll
  for (int rr = 0; rr < 32; rr += 8)
    d[(size_t)(c0 + ty + rr) * R + r0 + tx] = (f16)tile[tx][ty + rr];
}

// ---------------- router: logits, softmax, top-2, gates, per-block prob sums ----------------
__global__ void router_k(const float* __restrict__ x, const float* __restrict__ rw,
                         int* __restrict__ eidx, float* __restrict__ gates,
                         float* __restrict__ bps) {
  __shared__ float lrw[EDIM * DDIM];   // 32 KiB
  __shared__ float wps[4][EDIM];
  const int tid = threadIdx.x, lane = tid & 63, wv = tid >> 6;
  for (int i = tid; i < EDIM * DDIM; i += 256) lrw[i] = rw[i];
  __syncthreads();
  const int t = blockIdx.x * 4 + wv;
  float acc[EDIM];
  #pragma unroll
  for (int e = 0; e < EDIM; ++e) acc[e] = 0.f;
  const float* xr = x + (size_t)t * DDIM;
  #pragma unroll
  for (int j = 0; j < DDIM / 64; ++j) {
    float xv = xr[j * 64 + lane];
    #pragma unroll
    for (int e = 0; e < EDIM; ++e) acc[e] += xv * lrw[e * DDIM + j * 64 + lane];
  }
  #pragma unroll
  for (int off = 32; off >= 1; off >>= 1) {
    #pragma unroll
    for (int e = 0; e < EDIM; ++e) acc[e] += __shfl_xor(acc[e], off);
  }
  // softmax (all lanes redundantly)
  float mx = acc[0];
  #pragma unroll
  for (int e = 1; e < EDIM; ++e) mx = fmaxf(mx, acc[e]);
  float p[EDIM], s = 0.f;
  #pragma unroll
  for (int e = 0; e < EDIM; ++e) { p[e] = expf(acc[e] - mx); s += p[e]; }
  float inv = 1.f / s;
  #pragma unroll
  for (int e = 0; e < EDIM; ++e) p[e] *= inv;
  // top-2, ties -> lowest index (matches lax.top_k)
  int i1 = 0; float p1 = p[0];
  #pragma unroll
  for (int e = 1; e < EDIM; ++e) if (p[e] > p1) { p1 = p[e]; i1 = e; }
  int i2 = (i1 == 0) ? 1 : 0; float p2 = p[i2];
  #pragma unroll
  for (int e = 0; e < EDIM; ++e) if (e != i1 && p[e] > p2) { p2 = p[e]; i2 = e; }
  float gs = 1.f / (p1 + p2);
  if (lane == 0) {
    eidx[2 * t] = i1; eidx[2 * t + 1] = i2;
    gates[2 * t] = p1 * gs; gates[2 * t + 1] = p2 * gs;
    #pragma unroll
    for (int e = 0; e < EDIM; ++e) wps[wv][e] = p[e];
  }
  __syncthreads();
  if (tid < EDIM)
    bps[blockIdx.x * EDIM + tid] = wps[0][tid] + wps[1][tid] + wps[2][tid] + wps[3][tid];
}

// ---------------- per-chunk expert histogram (chunk = 256 slots) ----------------
__global__ void count_k(const int* __restrict__ eidx, int* __restrict__ cc) {
  __shared__ int h[EDIM];
  const int tid = threadIdx.x;
  if (tid < EDIM) h[tid] = 0;
  __syncthreads();
  atomicAdd(&h[eidx[blockIdx.x * 256 + tid]], 1);
  __syncthreads();
  if (tid < EDIM) cc[blockIdx.x * EDIM + tid] = h[tid];
}

// ---------------- scan chunks, totals, lb_loss ----------------
__global__ void scan_k(const int* __restrict__ cc, const float* __restrict__ bps,
                       int* __restrict__ cb, int* __restrict__ counts,
                       int* __restrict__ rowsNeeded, float* __restrict__ lb_out) {
  __shared__ float red[32][EDIM];
  __shared__ int cnt_s[EDIM];
  const int tid = threadIdx.x;
  const int e = tid & 7, g = tid >> 3;   // g in [0,32)
  float s = 0.f;
  for (int j = 0; j < 32; ++j) s += bps[(g + 32 * j) * EDIM + e];
  red[g][e] = s;
  __syncthreads();
  for (int st = 16; st >= 1; st >>= 1) {
    if (g < st) red[g][e] += red[g + st][e];
    __syncthreads();
  }
  if (tid < EDIM) {
    int base = 0;
    for (int c = 0; c < 32; ++c) { cb[c * EDIM + tid] = base; base += cc[c * EDIM + tid]; }
    counts[tid] = base;
    rowsNeeded[tid] = base < CAPD ? base : CAPD;
    cnt_s[tid] = base;
  }
  __syncthreads();
  if (tid == 0) {
    float lb = 0.f;
    for (int ee = 0; ee < EDIM; ++ee)
      lb += (red[0][ee] / (float)TDIM) * ((float)cnt_s[ee] / (float)NSLOT);
    lb_out[0] = lb * (float)EDIM;
  }
}

// ---------------- per-slot position via wave ballots (deterministic) ----------------
__global__ void pos_k(const int* __restrict__ eidx, const float* __restrict__ gates,
                      const int* __restrict__ cb, int* __restrict__ posa,
                      float* __restrict__ wslot) {
  __shared__ int wcnt[4][EDIM];
  const int tid = threadIdx.x, lane = tid & 63, wv = tid >> 6;
  const int slot = blockIdx.x * 256 + tid;
  const int e = eidx[slot];
  const unsigned long long below = (1ull << lane) - 1ull;
  int wavepos = 0;
  #pragma unroll
  for (int ee = 0; ee < EDIM; ++ee) {
    unsigned long long m = __ballot(e == ee);
    if (lane == 0) wcnt[wv][ee] = __popcll(m);
    if (e == ee) wavepos = __popcll(m & below);
  }
  __syncthreads();
  int off = 0;
  for (int w = 0; w < wv; ++w) off += wcnt[w][e];
  const int pos = cb[blockIdx.x * EDIM + e] + off + wavepos;
  posa[slot] = pos;
  wslot[slot] = (pos < CAPD) ? gates[slot] : 0.f;
}

// ---------------- scatter token rows -> f16 expert buffers ----------------
__global__ void scatter_k(const float* __restrict__ x, const int* __restrict__ eidx,
                          const int* __restrict__ posa, f16* __restrict__ buf) {
  const int s = blockIdx.x, lane = threadIdx.x;   // 64 threads
  const int p = posa[s];
  if (p >= CAPD) return;
  const int e = eidx[s], tok = s >> 1;
  const float4* src = (const float4*)(x + (size_t)tok * DDIM);
  f16x4* dst = (f16x4*)(buf + ((size_t)e * CAPD + p) * DDIM);
  #pragma unroll
  for (int j = 0; j < DDIM / 4 / 64; ++j) {
    float4 v = src[j * 64 + lane];
    f16x4 o; o.x = (f16)v.x; o.y = (f16)v.y; o.z = (f16)v.z; o.w = (f16)v.w;
    dst[j * 64 + lane] = o;
  }
}

// ---------------- 128x128 f16 MFMA GEMM (m97 structure), B pre-transposed (N,K) ----------------
template<int K, int N, int GELU>
__global__ __launch_bounds__(256)
void gemm_f16(const f16* __restrict__ A, const f16* __restrict__ Bt,
              const float* __restrict__ bias, f16* __restrict__ C,
              const int* __restrict__ rowsNeeded) {
  constexpr int MMAX = CAPD;
  const int e = blockIdx.z, mt = blockIdx.y, nt = blockIdx.x;
  if (mt * 128 >= rowsNeeded[e]) return;
  __shared__ f16 As[128 * 64];
  __shared__ f16 Bs[128 * 64];
  const int tid = threadIdx.x, lane = tid & 63, wv = tid >> 6;
  const int wr = wv >> 1, wc = wv & 1;
  const size_t abase = ((size_t)e * MMAX + (size_t)mt * 128) * K;
  const size_t bbase = ((size_t)e * N + (size_t)nt * 128) * K;
  const int srow = tid >> 3;            // row-in-32 block
  const int scol = (tid & 7) * 8;       // f16 elements
  const f16* aSrc = A + abase + (size_t)srow * K + scol;
  const f16* bSrc = Bt + bbase + (size_t)srow * K + scol;
  char* asDst = (char*)As + wv * 1024;  // wave-uniform LDS base
  char* bsDst = (char*)Bs + wv * 1024;

  f32x4 acc[4][4];
  #pragma unroll
  for (int m = 0; m < 4; ++m)
    #pragma unroll
    for (int n = 0; n < 4; ++n) acc[m][n] = (f32x4){0.f, 0.f, 0.f, 0.f};

  const int ro = lane & 15, ko0 = (lane >> 4) * 8;

  #pragma unroll 1
  for (int kt = 0; kt < K / 64; ++kt) {
    const int k0 = kt * 64;
    __syncthreads();
    #pragma unroll
    for (int i = 0; i < 4; ++i) {
      gload16(aSrc + (size_t)(i * 32) * K + k0, asDst + i * 4096);
      gload16(bSrc + (size_t)(i * 32) * K + k0, bsDst + i * 4096);
    }
    __syncthreads();
    #pragma unroll
    for (int kk = 0; kk < 64; kk += 32) {
      f16x8 a[4], b[4];
      #pragma unroll
      for (int m = 0; m < 4; ++m)
        a[m] = *(const f16x8*)(As + (wr * 64 + m * 16 + ro) * 64 + kk + ko0);
      #pragma unroll
      for (int n = 0; n < 4; ++n)
        b[n] = *(const f16x8*)(Bs + (wc * 64 + n * 16 + ro) * 64 + kk + ko0);
      #pragma unroll
      for (int m = 0; m < 4; ++m)
        #pragma unroll
        for (int n = 0; n < 4; ++n)
          acc[m][n] = __builtin_amdgcn_mfma_f32_16x16x32_f16(a[m], b[n], acc[m][n], 0, 0, 0);
    }
  }

  const int rowb = mt * 128 + wr * 64;
  const int colb = nt * 128 + wc * 64;
  #pragma unroll
  for (int m = 0; m < 4; ++m) {
    #pragma unroll
    for (int n = 0; n < 4; ++n) {
      const int col = colb + n * 16 + ro;
      const float bv = bias[e * N + col];
      #pragma unroll
      for (int i = 0; i < 4; ++i) {
        const int row = rowb + m * 16 + (lane >> 4) * 4 + i;
        float v = acc[m][n][i] + bv;
        if (GELU) v = 0.5f * v * (1.f + erff(v * 0.70710678118654752f));
        C[((size_t)e * MMAX + row) * N + col] = (f16)v;
      }
    }
  }
}

// ---------------- combine: out[t] = sum_k wslot * oute[row] ----------------
__global__ void combine_k(const f16* __restrict__ oute, const int* __restrict__ eidx,
                          const int* __restrict__ posa, const float* __restrict__ wslot,
                          float* __restrict__ out) {
  const int t = blockIdx.x, tid = threadIdx.x;
  const int s0 = 2 * t, s1 = 2 * t + 1;
  const int e0 = eidx[s0], e1 = eidx[s1];
  int p0 = posa[s0]; p0 = p0 < CAPD - 1 ? p0 : CAPD - 1;
  int p1 = posa[s1]; p1 = p1 < CAPD - 1 ? p1 : CAPD - 1;
  const float g0 = wslot[s0], g1 = wslot[s1];
  const f16x2* r0 = (const f16x2*)(oute + ((size_t)e0 * CAPD + p0) * DDIM);
  const f16x2* r1 = (const f16x2*)(oute + ((size_t)e1 * CAPD + p1) * DDIM);
  float2* o = (float2*)(out + (size_t)t * DDIM);
  #pragma unroll
  for (int j = tid; j < DDIM / 2; j += 256) {
    f16x2 a = r0[j], b = r1[j];
    o[j] = make_float2(g0 * (float)a.x + g1 * (float)b.x,
                       g0 * (float)a.y + g1 * (float)b.y);
  }
}

extern "C" void kernel_launch(void* const* d_in, const int* in_sizes, int n_in,
                              void* d_out, int out_size, void* d_ws, size_t ws_size,
                              hipStream_t stream) {
  (void)in_sizes; (void)n_in; (void)out_size; (void)ws_size;
  const float* x  = (const float*)d_in[0];
  const float* rw = (const float*)d_in[1];
  const float* w1 = (const float*)d_in[2];
  const float* b1 = (const float*)d_in[3];
  const float* w2 = (const float*)d_in[4];
  const float* b2 = (const float*)d_in[5];
  float* out = (float*)d_out;

  char* ws = (char*)d_ws;
  size_t off = 0;
  auto alloc = [&](size_t b) { void* p = ws + off; off += (b + 255) & ~(size_t)255; return p; };
  f16* w1t   = (f16*)alloc((size_t)EDIM * DDIM * HDIM * 2);   // (E,H,D)
  f16* w2t   = (f16*)alloc((size_t)EDIM * DDIM * HDIM * 2);   // (E,D,H)
  f16* buf   = (f16*)alloc((size_t)EDIM * CAPD * DDIM * 2);   // (E,CAP,D)
  f16* hbuf  = (f16*)alloc((size_t)EDIM * CAPD * HDIM * 2);   // (E,CAP,H)
  f16* oute  = (f16*)alloc((size_t)EDIM * CAPD * DDIM * 2);   // (E,CAP,D)
  int*   eidx   = (int*)alloc(NSLOT * 4);
  int*   posa   = (int*)alloc(NSLOT * 4);
  float* gatesA = (float*)alloc(NSLOT * 4);
  float* wslotA = (float*)alloc(NSLOT * 4);
  int*   cc     = (int*)alloc(32 * EDIM * 4);
  int*   cb     = (int*)alloc(32 * EDIM * 4);
  int*   counts = (int*)alloc(EDIM * 4);
  int*   rowsN  = (int*)alloc(EDIM * 4);
  float* bps    = (float*)alloc(NROUTERBLK * EDIM * 4);

  // weight conversion (independent of routing chain)
  transpose_cvt<<<dim3(HDIM / 32, DDIM / 32, EDIM), 256, 0, stream>>>(w1, w1t, DDIM, HDIM);
  transpose_cvt<<<dim3(DDIM / 32, HDIM / 32, EDIM), 256, 0, stream>>>(w2, w2t, HDIM, DDIM);

  // routing chain
  router_k<<<NROUTERBLK, 256, 0, stream>>>(x, rw, eidx, gatesA, bps);
  count_k<<<32, 256, 0, stream>>>(eidx, cc);
  scan_k<<<1, 256, 0, stream>>>(cc, bps, cb, counts, rowsN, out + (size_t)TDIM * DDIM);
  pos_k<<<32, 256, 0, stream>>>(eidx, gatesA, cb, posa, wslotA);
  scatter_k<<<NSLOT, 64, 0, stream>>>(x, eidx, posa, buf);

  // expert GEMMs
  gemm_f16<DDIM, HDIM, 1><<<dim3(HDIM / 128, CAPD / 128, EDIM), 256, 0, stream>>>(
      buf, w1t, b1, hbuf, rowsN);
  gemm_f16<HDIM, DDIM, 0><<<dim3(DDIM / 128, CAPD / 128, EDIM), 256, 0, stream>>>(
      hbuf, w2t, b2, oute, rowsN);

  // combine
  combine_k<<<TDIM, 256, 0, stream>>>(oute, eidx, posa, wslotA, out);
}